// Round 1
// baseline (89.372 us; speedup 1.0000x reference)
//
#include <hip/hip_runtime.h>
#include <math.h>

constexpr int NUM_ELS   = 262144;
constexpr int NUM_NODES = 32768;
constexpr int MAX_CHS   = 32;
constexpr int BATCH     = 128;

__global__ __launch_bounds__(BATCH) void sum_layer_kernel(
    const float* __restrict__ em,
    const float* __restrict__ params,
    const int*   __restrict__ cids,
    const int*   __restrict__ pids,
    float*       __restrict__ out)
{
    const int node = blockIdx.x;      // uniform per block -> scalar loads for cids/pids/params
    const int b    = threadIdx.x;     // batch column; lanes 0..63 coalesce 256B per row
    const int base = node * MAX_CHS;

    // Stage all 32 gathered child values into registers (static indices ->
    // stays in VGPRs; all 32 global loads issued back-to-back for MLP).
    float v[MAX_CHS];
#pragma unroll
    for (int c = 0; c < MAX_CHS; ++c) {
        const int cid = cids[base + c];
        v[c] = em[(size_t)cid * BATCH + b];
    }

    // Max over children.
    float m = v[0];
#pragma unroll
    for (int c = 1; c < MAX_CHS; ++c) m = fmaxf(m, v[c]);

    // Weighted sum of exp(v - m).
    float s = 0.0f;
#pragma unroll
    for (int c = 0; c < MAX_CHS; ++c) {
        const float w = params[pids[base + c]];   // uniform per block
        s = __builtin_fmaf(__expf(v[c] - m), w, s);
    }

    out[(size_t)node * BATCH + b] = __logf(fmaxf(s, 1e-10f)) + m;
}

extern "C" void kernel_launch(void* const* d_in, const int* in_sizes, int n_in,
                              void* d_out, int out_size, void* d_ws, size_t ws_size,
                              hipStream_t stream)
{
    const float* em     = (const float*)d_in[0];
    const float* params = (const float*)d_in[1];
    const int*   cids   = (const int*)d_in[2];
    const int*   pids   = (const int*)d_in[3];
    float*       out    = (float*)d_out;

    sum_layer_kernel<<<NUM_NODES, BATCH, 0, stream>>>(em, params, cids, pids, out);
}